// Round 13
// baseline (178.443 us; speedup 1.0000x reference)
//
#include <hip/hip_runtime.h>
#include <hip/hip_bf16.h>

#define NN 256
#define NH 8
#define NB 4
#define NPOS (NB * NN * NN)   // 262144 positions (b,n,m)

typedef float f32x4 __attribute__((ext_vector_type(4)));
typedef short bf16x8 __attribute__((ext_vector_type(8)));
typedef unsigned int uint32_tt;

static __device__ __forceinline__ short f2bf(float f) {
    __hip_bfloat16 h = __float2bfloat16(f);
    union { __hip_bfloat16 b; short s; } u; u.b = h; return u.s;
}

// 4 independent global_load_dwordx4 from one base, literal offsets.
// asm outputs cannot be sunk or rematerialized -> pipeline survives regalloc.
#define GL4(d0, d1, d2, d3, voff, base, O0, O1, O2, O3)                     \
    asm volatile("global_load_dwordx4 %0, %4, %5 offset:" #O0 "\n\t"        \
                 "global_load_dwordx4 %1, %4, %5 offset:" #O1 "\n\t"        \
                 "global_load_dwordx4 %2, %4, %5 offset:" #O2 "\n\t"        \
                 "global_load_dwordx4 %3, %4, %5 offset:" #O3               \
                 : "=&v"(d0), "=&v"(d1), "=&v"(d2), "=&v"(d3)               \
                 : "v"(voff), "s"(base) : "memory")

// ---------------------------------------------------------------------------
// Kernel 0 (init): build per-lane B-fragments of W^T in GLOBAL scratch
// (wfragG[lane][s][j] = bf16(W[s*32 + (lane>>4)*8 + j][lane&15]), zero for
// col>=8). 16KB, L2-hot for the attn kernel. Also clears maskw.
// ---------------------------------------------------------------------------
__global__ void init_kernel(const float* __restrict__ W,
                            short* __restrict__ wfragG,
                            unsigned int* __restrict__ maskw)
{
    const int l = threadIdx.x;          // 0..63
    const int r15 = l & 15;
    const int kg = l >> 4;
    for (int s = 0; s < 16; ++s)
        for (int j = 0; j < 8; ++j) {
            const int kk = s * 32 + kg * 8 + j;
            const float v = (r15 < 8) ? W[(size_t)kk * NH + r15] : 0.f;
            wfragG[(size_t)l * 128 + s * 8 + j] = f2bf(v);
        }
    if (l < 8) maskw[l] = 0u;
}

// ---------------------------------------------------------------------------
// Kernel 1 (MFMA, deep-MLP): attn = sigmoid([NPOS x 512] @ W[512 x 8] + b)
// One wave = 16 positions. R12 diagnosis: VGPR=48 proves the compiler rolled
// the 32-load pipeline into load->cvt->mfma (2 loads in flight, pure exposed
// latency; VALU 4%, MFMA 1%). Fix: 48 inline-asm loads (16 wfrag + 32 q/k),
// ZERO LDS / barriers (wfrag precomputed in global), ONE vmcnt(0) drain +
// sched_barrier, then cvt + 16 MFMA + store. ~210 VGPR < 256 cap at
// __launch_bounds__(256,2); 8 waves/CU x 48KB in flight each.
// ---------------------------------------------------------------------------
__global__ __launch_bounds__(256, 2) void attn_kernel(
    const float* __restrict__ q, const float* __restrict__ k,
    const short* __restrict__ wfragG, const float* __restrict__ bias,
    float* __restrict__ attn)
{
    const int tid = threadIdx.x;
    const int lane = tid & 63;
    const int wid = tid >> 6;
    const int r15 = lane & 15;          // A row / C col
    const int kg  = lane >> 4;          // k-group 0..3

    const int gwave = blockIdx.x * 4 + wid;      // 0..16383
    const int p0 = gwave * 16;

    const unsigned int voffqk =
        (unsigned int)(p0 + r15) * 1024u + (unsigned int)kg * 32u;
    const unsigned int voffw = (unsigned int)lane * 256u;

    const float bb = (r15 < 8) ? bias[r15] : 0.f;

    bf16x8 wf[16];
    f32x4 qlo[8], qhi[8], klo[8], khi[8];

    // ---- issue all 48 loads back-to-back (stay in flight together) ----
    GL4(wf[0],  wf[1],  wf[2],  wf[3],  voffw, wfragG,   0,  16,  32,  48);
    GL4(wf[4],  wf[5],  wf[6],  wf[7],  voffw, wfragG,  64,  80,  96, 112);
    GL4(wf[8],  wf[9],  wf[10], wf[11], voffw, wfragG, 128, 144, 160, 176);
    GL4(wf[12], wf[13], wf[14], wf[15], voffw, wfragG, 192, 208, 224, 240);

    GL4(qlo[0], qhi[0], qlo[1], qhi[1], voffqk, q,   0,  16, 128, 144);
    GL4(qlo[2], qhi[2], qlo[3], qhi[3], voffqk, q, 256, 272, 384, 400);
    GL4(qlo[4], qhi[4], qlo[5], qhi[5], voffqk, q, 512, 528, 640, 656);
    GL4(qlo[6], qhi[6], qlo[7], qhi[7], voffqk, q, 768, 784, 896, 912);

    GL4(klo[0], khi[0], klo[1], khi[1], voffqk, k,   0,  16, 128, 144);
    GL4(klo[2], khi[2], klo[3], khi[3], voffqk, k, 256, 272, 384, 400);
    GL4(klo[4], khi[4], klo[5], khi[5], voffqk, k, 512, 528, 640, 656);
    GL4(klo[6], khi[6], klo[7], khi[7], voffqk, k, 768, 784, 896, 912);

    asm volatile("s_waitcnt vmcnt(0)" ::: "memory");
    __builtin_amdgcn_sched_barrier(0);   // rule #18: no hoisting above the wait

    // ---- convert to bf16 fragments ----
    bf16x8 afrag[16];
#pragma unroll
    for (int s = 0; s < 8; ++s) {
        afrag[s][0] = f2bf(qlo[s].x); afrag[s][1] = f2bf(qlo[s].y);
        afrag[s][2] = f2bf(qlo[s].z); afrag[s][3] = f2bf(qlo[s].w);
        afrag[s][4] = f2bf(qhi[s].x); afrag[s][5] = f2bf(qhi[s].y);
        afrag[s][6] = f2bf(qhi[s].z); afrag[s][7] = f2bf(qhi[s].w);
        afrag[8+s][0] = f2bf(klo[s].x); afrag[8+s][1] = f2bf(klo[s].y);
        afrag[8+s][2] = f2bf(klo[s].z); afrag[8+s][3] = f2bf(klo[s].w);
        afrag[8+s][4] = f2bf(khi[s].x); afrag[8+s][5] = f2bf(khi[s].y);
        afrag[8+s][6] = f2bf(khi[s].z); afrag[8+s][7] = f2bf(khi[s].w);
    }

    f32x4 acc = {0.f, 0.f, 0.f, 0.f};
#pragma unroll
    for (int s = 0; s < 16; ++s)
        acc = __builtin_amdgcn_mfma_f32_16x16x32_bf16(afrag[s], wf[s], acc,
                                                      0, 0, 0);

    // epilogue: C[row=kg*4+i][col=r15], cols 0..7 valid (verified R12)
    if (r15 < 8) {
#pragma unroll
        for (int i = 0; i < 4; ++i) {
            const int pos = p0 + kg * 4 + i;
            const float s = 1.f / (1.f + __expf(-(acc[i] + bb)));
            attn[(size_t)pos * NH + r15] = s;
        }
    }
}

// ---------------------------------------------------------------------------
// Kernel 2: dim2_mask union of top-k / bottom-k indices (exact rank count,
// matches jax.lax.top_k stable tie-breaking). Register-accumulated selection,
// ballot + 2 atomicOr per wave; 64 publisher blocks seed the mask per-task;
// everyone early-exits on full mask via volatile loads (monotonic bits =>
// stale reads are safe).
// ---------------------------------------------------------------------------
__global__ __launch_bounds__(256) void topk_kernel(
    const float* __restrict__ attn, const float* __restrict__ m1,
    const float* __restrict__ m2, unsigned int* __restrict__ maskw)
{
    __shared__ __align__(16) float a[NN];
    __shared__ int snotfull;
    const int tid = threadIdx.x;
    const int T = 2 * NB * NN * NH;   // 16384 tasks
    const bool publisher = (blockIdx.x < 64);
    const volatile unsigned int* vmask = maskw;
    bool selAcc = false;
    bool broke = false;

    for (int t = blockIdx.x; t < T; t += gridDim.x) {
        if (t != (int)blockIdx.x) {
            if (tid == 0) snotfull = 0;
            __syncthreads();
            if (tid < 8 && vmask[tid] != 0xFFFFFFFFu) snotfull = 1;
            __syncthreads();
            if (!snotfull) { broke = true; break; }
        }

        const int variant = t >> 13;
        const int r = t & 8191;
        const int h = r & 7;
        const int n = (r >> 3) & 255;
        const int b = r >> 11;
        const size_t rowBase = ((size_t)(b * NN + n)) * NN;
        const float* mk = variant ? m2 : m1;
        const int kt = variant ? 128 : 64;
        const int kb = 64;

        a[tid] = attn[(rowBase + tid) * NH + h] * mk[rowBase + tid];
        __syncthreads();

        const float av = a[tid];
        int gt = 0, lt = 0, el = 0;
#pragma unroll 8
        for (int u4 = 0; u4 < NN / 4; ++u4) {
            const f32x4 w = *reinterpret_cast<const f32x4*>(&a[u4 * 4]);
            const int u = u4 * 4;
            gt += (w.x > av) + (w.y > av) + (w.z > av) + (w.w > av);
            lt += (w.x < av) + (w.y < av) + (w.z < av) + (w.w < av);
            el += ((w.x == av) & (u + 0 < tid)) + ((w.y == av) & (u + 1 < tid))
                + ((w.z == av) & (u + 2 < tid)) + ((w.w == av) & (u + 3 < tid));
        }
        const bool sel = ((gt + el) < kt) || ((lt + el) < kb);
        selAcc |= sel;

        if (publisher) {
            const unsigned long long bal = __ballot(sel);
            if ((tid & 63) == 0) {
                const int w = tid >> 6;
                atomicOr(&maskw[w * 2 + 0], (unsigned int)(bal & 0xFFFFFFFFull));
                atomicOr(&maskw[w * 2 + 1], (unsigned int)(bal >> 32));
            }
        }
        __syncthreads();
    }

    if (!broke && !publisher) {
        const unsigned long long bal = __ballot(selAcc);
        if ((tid & 63) == 0) {
            const int w = tid >> 6;
            atomicOr(&maskw[w * 2 + 0], (unsigned int)(bal & 0xFFFFFFFFull));
            atomicOr(&maskw[w * 2 + 1], (unsigned int)(bal >> 32));
        }
    }
}

// ---------------------------------------------------------------------------
// Kernel 3: out *= (m1+m2) * dim2_mask[m], in place, float4 over H.
// ---------------------------------------------------------------------------
__global__ __launch_bounds__(256) void finalize_kernel(
    float* __restrict__ out, const float* __restrict__ m1,
    const float* __restrict__ m2, const unsigned int* __restrict__ maskw)
{
    const int total = NPOS * 2;       // float4 units (H=8 -> 2 per position)
    for (int i4 = blockIdx.x * blockDim.x + threadIdx.x; i4 < total;
         i4 += gridDim.x * blockDim.x) {
        const int m = (i4 >> 1) & 255;
        const int bn = i4 >> 9;
        const float bit = ((maskw[m >> 5] >> (m & 31)) & 1u) ? 1.f : 0.f;
        const size_t mi = (size_t)bn * NN + m;
        const float scale = (m1[mi] + m2[mi]) * bit;
        f32x4 v = reinterpret_cast<f32x4*>(out)[i4];
        v.x *= scale; v.y *= scale; v.z *= scale; v.w *= scale;
        reinterpret_cast<f32x4*>(out)[i4] = v;
    }
}

extern "C" void kernel_launch(void* const* d_in, const int* in_sizes, int n_in,
                              void* d_out, int out_size, void* d_ws, size_t ws_size,
                              hipStream_t stream) {
    const float* q    = (const float*)d_in[0];
    const float* kk   = (const float*)d_in[1];
    const float* m1   = (const float*)d_in[2];
    const float* m2   = (const float*)d_in[3];
    const float* W    = (const float*)d_in[4];
    const float* bias = (const float*)d_in[5];
    float* out = (float*)d_out;

    unsigned int* maskw = (unsigned int*)d_ws;
    short* wfragG = (short*)((char*)d_ws + 256);   // 16KB fragment table

    hipLaunchKernelGGL(init_kernel, dim3(1), dim3(64), 0, stream,
                       W, wfragG, maskw);
    // 4096 blocks * 4 waves = 16384 waves; 16 positions each = NPOS exactly
    hipLaunchKernelGGL(attn_kernel, dim3(4096), dim3(256), 0, stream,
                       q, kk, wfragG, bias, out);
    hipLaunchKernelGGL(topk_kernel, dim3(1024), dim3(256), 0, stream,
                       out, m1, m2, maskw);
    hipLaunchKernelGGL(finalize_kernel, dim3(2048), dim3(256), 0, stream,
                       out, m1, m2, maskw);
}

// Round 14
// 165.627 us; speedup vs baseline: 1.0774x; 1.0774x over previous
//
#include <hip/hip_runtime.h>
#include <hip/hip_bf16.h>

#define NN 256
#define NH 8
#define NB 4
#define NPOS (NB * NN * NN)   // 262144 positions (b,n,m)

typedef float f32x4 __attribute__((ext_vector_type(4)));
typedef short bf16x8 __attribute__((ext_vector_type(8)));

static __device__ __forceinline__ short f2bf(float f) {
    __hip_bfloat16 h = __float2bfloat16(f);
    union { __hip_bfloat16 b; short s; } u; u.b = h; return u.s;
}

// 4 independent global_load_dwordx4 from one base, literal offsets.
#define GL4(d0, d1, d2, d3, voff, base, O0, O1, O2, O3)                     \
    asm volatile("global_load_dwordx4 %0, %4, %5 offset:" #O0 "\n\t"        \
                 "global_load_dwordx4 %1, %4, %5 offset:" #O1 "\n\t"        \
                 "global_load_dwordx4 %2, %4, %5 offset:" #O2 "\n\t"        \
                 "global_load_dwordx4 %3, %4, %5 offset:" #O3               \
                 : "=&v"(d0), "=&v"(d1), "=&v"(d2), "=&v"(d3)               \
                 : "v"(voff), "s"(base) : "memory")

// R13 lesson (rule #18 variant): compiler hoists register-only consume code
// BETWEEN asm blocks, adding its own waitcnts -> stream re-serialized,
// VGPR=100 instead of ~210. Pin with a sched_barrier after EVERY group.
#define SB __builtin_amdgcn_sched_barrier(0)

// ---------------------------------------------------------------------------
// Kernel 0 (init, parallel): build per-lane B-fragments of W^T in global
// scratch: wfragG[l][s][j] = bf16(W[s*32+(l>>4)*8+j][l&15]), 0 for col>=8.
// 1024 threads, 8 scalar reads each (~2us). Also clears maskw.
// ---------------------------------------------------------------------------
__global__ void init_kernel(const float* __restrict__ W,
                            short* __restrict__ wfragG,
                            unsigned int* __restrict__ maskw)
{
    const int t = blockIdx.x * blockDim.x + threadIdx.x;   // 0..1023
    if (t < 8) maskw[t] = 0u;
    if (t >= 1024) return;
    const int l = t >> 4;               // lane 0..63
    const int s = t & 15;               // K-step 0..15
    const int r15 = l & 15;
    const int kg = l >> 4;
    bf16x8 v;
#pragma unroll
    for (int j = 0; j < 8; ++j) {
        const int kk = s * 32 + kg * 8 + j;
        v[j] = (r15 < 8) ? f2bf(W[(size_t)kk * NH + r15]) : (short)0;
    }
    *(bf16x8*)(&wfragG[(size_t)l * 128 + s * 8]) = v;
}

// ---------------------------------------------------------------------------
// Kernel 1 (MFMA): attn = sigmoid([NPOS x 512] @ W[512 x 8] + b)
// One wave = 16 positions. 48 inline-asm dwordx4 (16 wfrag L2-hot + 32 q/k),
// sched_barrier(0) between ALL groups (no interleaved consumption), ONE
// vmcnt(0) drain, cvt, 16 x mfma_f32_16x16x32_bf16, store. ~210 VGPR live at
// the drain; __launch_bounds__(256,1) caps at 256 so it fits (R10 lesson:
// demand > cap silently collapses the pipeline). 8 waves/CU x 48KB in flight
// = 384KB/CU >> BW*latency (~35KB at ~3400cy loaded latency).
// ---------------------------------------------------------------------------
__global__ __launch_bounds__(256, 1) void attn_kernel(
    const float* __restrict__ q, const float* __restrict__ k,
    const short* __restrict__ wfragG, const float* __restrict__ bias,
    float* __restrict__ attn)
{
    const int tid = threadIdx.x;
    const int lane = tid & 63;
    const int wid = tid >> 6;
    const int r15 = lane & 15;          // A row / C col
    const int kg  = lane >> 4;          // k-group 0..3

    const int gwave = blockIdx.x * 4 + wid;      // 0..16383
    const int p0 = gwave * 16;

    const unsigned int voffqk =
        (unsigned int)(p0 + r15) * 1024u + (unsigned int)kg * 32u;
    const unsigned int voffw = (unsigned int)lane * 256u;

    const float bb = (r15 < 8) ? bias[r15] : 0.f;

    bf16x8 wf[16];
    f32x4 qlo[8], qhi[8], klo[8], khi[8];

    // ---- 48 loads, all outstanding together (SB pins: nothing between) ----
    GL4(qlo[0], qhi[0], qlo[1], qhi[1], voffqk, q,   0,  16, 128, 144); SB;
    GL4(qlo[2], qhi[2], qlo[3], qhi[3], voffqk, q, 256, 272, 384, 400); SB;
    GL4(qlo[4], qhi[4], qlo[5], qhi[5], voffqk, q, 512, 528, 640, 656); SB;
    GL4(qlo[6], qhi[6], qlo[7], qhi[7], voffqk, q, 768, 784, 896, 912); SB;

    GL4(klo[0], khi[0], klo[1], khi[1], voffqk, k,   0,  16, 128, 144); SB;
    GL4(klo[2], khi[2], klo[3], khi[3], voffqk, k, 256, 272, 384, 400); SB;
    GL4(klo[4], khi[4], klo[5], khi[5], voffqk, k, 512, 528, 640, 656); SB;
    GL4(klo[6], khi[6], klo[7], khi[7], voffqk, k, 768, 784, 896, 912); SB;

    GL4(wf[0],  wf[1],  wf[2],  wf[3],  voffw, wfragG,   0,  16,  32,  48); SB;
    GL4(wf[4],  wf[5],  wf[6],  wf[7],  voffw, wfragG,  64,  80,  96, 112); SB;
    GL4(wf[8],  wf[9],  wf[10], wf[11], voffw, wfragG, 128, 144, 160, 176); SB;
    GL4(wf[12], wf[13], wf[14], wf[15], voffw, wfragG, 192, 208, 224, 240); SB;

    asm volatile("s_waitcnt vmcnt(0)" ::: "memory");
    SB;   // rule #18: no hoisting above the wait

    // ---- convert to bf16 fragments ----
    bf16x8 afrag[16];
#pragma unroll
    for (int s = 0; s < 8; ++s) {
        afrag[s][0] = f2bf(qlo[s].x); afrag[s][1] = f2bf(qlo[s].y);
        afrag[s][2] = f2bf(qlo[s].z); afrag[s][3] = f2bf(qlo[s].w);
        afrag[s][4] = f2bf(qhi[s].x); afrag[s][5] = f2bf(qhi[s].y);
        afrag[s][6] = f2bf(qhi[s].z); afrag[s][7] = f2bf(qhi[s].w);
        afrag[8+s][0] = f2bf(klo[s].x); afrag[8+s][1] = f2bf(klo[s].y);
        afrag[8+s][2] = f2bf(klo[s].z); afrag[8+s][3] = f2bf(klo[s].w);
        afrag[8+s][4] = f2bf(khi[s].x); afrag[8+s][5] = f2bf(khi[s].y);
        afrag[8+s][6] = f2bf(khi[s].z); afrag[8+s][7] = f2bf(khi[s].w);
    }

    f32x4 acc = {0.f, 0.f, 0.f, 0.f};
#pragma unroll
    for (int s = 0; s < 16; ++s)
        acc = __builtin_amdgcn_mfma_f32_16x16x32_bf16(afrag[s], wf[s], acc,
                                                      0, 0, 0);

    // epilogue: C[row=kg*4+i][col=r15], cols 0..7 valid (verified R12)
    if (r15 < 8) {
#pragma unroll
        for (int i = 0; i < 4; ++i) {
            const int pos = p0 + kg * 4 + i;
            const float s = 1.f / (1.f + __expf(-(acc[i] + bb)));
            attn[(size_t)pos * NH + r15] = s;
        }
    }
}

// ---------------------------------------------------------------------------
// Kernel 2: dim2_mask union of top-k / bottom-k indices (exact rank count,
// matches jax.lax.top_k stable tie-breaking). Register-accumulated selection,
// ballot + 2 atomicOr per wave; 64 publisher blocks seed the mask per-task;
// everyone early-exits on full mask via volatile loads (monotonic bits =>
// stale reads are safe).
// ---------------------------------------------------------------------------
__global__ __launch_bounds__(256) void topk_kernel(
    const float* __restrict__ attn, const float* __restrict__ m1,
    const float* __restrict__ m2, unsigned int* __restrict__ maskw)
{
    __shared__ __align__(16) float a[NN];
    __shared__ int snotfull;
    const int tid = threadIdx.x;
    const int T = 2 * NB * NN * NH;   // 16384 tasks
    const bool publisher = (blockIdx.x < 64);
    const volatile unsigned int* vmask = maskw;
    bool selAcc = false;
    bool broke = false;

    for (int t = blockIdx.x; t < T; t += gridDim.x) {
        if (t != (int)blockIdx.x) {
            if (tid == 0) snotfull = 0;
            __syncthreads();
            if (tid < 8 && vmask[tid] != 0xFFFFFFFFu) snotfull = 1;
            __syncthreads();
            if (!snotfull) { broke = true; break; }
        }

        const int variant = t >> 13;
        const int r = t & 8191;
        const int h = r & 7;
        const int n = (r >> 3) & 255;
        const int b = r >> 11;
        const size_t rowBase = ((size_t)(b * NN + n)) * NN;
        const float* mk = variant ? m2 : m1;
        const int kt = variant ? 128 : 64;
        const int kb = 64;

        a[tid] = attn[(rowBase + tid) * NH + h] * mk[rowBase + tid];
        __syncthreads();

        const float av = a[tid];
        int gt = 0, lt = 0, el = 0;
#pragma unroll 8
        for (int u4 = 0; u4 < NN / 4; ++u4) {
            const f32x4 w = *reinterpret_cast<const f32x4*>(&a[u4 * 4]);
            const int u = u4 * 4;
            gt += (w.x > av) + (w.y > av) + (w.z > av) + (w.w > av);
            lt += (w.x < av) + (w.y < av) + (w.z < av) + (w.w < av);
            el += ((w.x == av) & (u + 0 < tid)) + ((w.y == av) & (u + 1 < tid))
                + ((w.z == av) & (u + 2 < tid)) + ((w.w == av) & (u + 3 < tid));
        }
        const bool sel = ((gt + el) < kt) || ((lt + el) < kb);
        selAcc |= sel;

        if (publisher) {
            const unsigned long long bal = __ballot(sel);
            if ((tid & 63) == 0) {
                const int w = tid >> 6;
                atomicOr(&maskw[w * 2 + 0], (unsigned int)(bal & 0xFFFFFFFFull));
                atomicOr(&maskw[w * 2 + 1], (unsigned int)(bal >> 32));
            }
        }
        __syncthreads();
    }

    if (!broke && !publisher) {
        const unsigned long long bal = __ballot(selAcc);
        if ((tid & 63) == 0) {
            const int w = tid >> 6;
            atomicOr(&maskw[w * 2 + 0], (unsigned int)(bal & 0xFFFFFFFFull));
            atomicOr(&maskw[w * 2 + 1], (unsigned int)(bal >> 32));
        }
    }
}

// ---------------------------------------------------------------------------
// Kernel 3: out *= (m1+m2) * dim2_mask[m], in place, float4 over H.
// ---------------------------------------------------------------------------
__global__ __launch_bounds__(256) void finalize_kernel(
    float* __restrict__ out, const float* __restrict__ m1,
    const float* __restrict__ m2, const unsigned int* __restrict__ maskw)
{
    const int total = NPOS * 2;       // float4 units (H=8 -> 2 per position)
    for (int i4 = blockIdx.x * blockDim.x + threadIdx.x; i4 < total;
         i4 += gridDim.x * blockDim.x) {
        const int m = (i4 >> 1) & 255;
        const int bn = i4 >> 9;
        const float bit = ((maskw[m >> 5] >> (m & 31)) & 1u) ? 1.f : 0.f;
        const size_t mi = (size_t)bn * NN + m;
        const float scale = (m1[mi] + m2[mi]) * bit;
        f32x4 v = reinterpret_cast<f32x4*>(out)[i4];
        v.x *= scale; v.y *= scale; v.z *= scale; v.w *= scale;
        reinterpret_cast<f32x4*>(out)[i4] = v;
    }
}

extern "C" void kernel_launch(void* const* d_in, const int* in_sizes, int n_in,
                              void* d_out, int out_size, void* d_ws, size_t ws_size,
                              hipStream_t stream) {
    const float* q    = (const float*)d_in[0];
    const float* kk   = (const float*)d_in[1];
    const float* m1   = (const float*)d_in[2];
    const float* m2   = (const float*)d_in[3];
    const float* W    = (const float*)d_in[4];
    const float* bias = (const float*)d_in[5];
    float* out = (float*)d_out;

    unsigned int* maskw = (unsigned int*)d_ws;
    short* wfragG = (short*)((char*)d_ws + 256);   // 16KB fragment table

    hipLaunchKernelGGL(init_kernel, dim3(4), dim3(256), 0, stream,
                       W, wfragG, maskw);
    // 4096 blocks * 4 waves = 16384 waves; 16 positions each = NPOS exactly
    hipLaunchKernelGGL(attn_kernel, dim3(4096), dim3(256), 0, stream,
                       q, kk, wfragG, bias, out);
    hipLaunchKernelGGL(topk_kernel, dim3(1024), dim3(256), 0, stream,
                       out, m1, m2, maskw);
    hipLaunchKernelGGL(finalize_kernel, dim3(2048), dim3(256), 0, stream,
                       out, m1, m2, maskw);
}